// Round 5
// baseline (11277.789 us; speedup 1.0000x reference)
//
#include <hip/hip_runtime.h>
#include <math.h>

// DigitCapsules dynamic routing, MI355X.
// x: [32, 2048, 16] f32   W: [2048, 64, 32, 16] f32   out: [32, 64, 32] f32
// Key algebra: b_r = u_hat * V_r with V_r = sum of previous v's  (b starts 0,
// updated b += u_hat*v). So we never materialize b or u_hat; each routing
// iteration is one streaming pass over W recomputing u_hat on the fly.

#define NB     32
#define NIN    2048
#define NOC    64
#define NOD    32
#define NK     16
#define NITERS 5
#define ICHUNK 16                 // in_caps per wave
#define NCHUNK (NIN / ICHUNK)     // 128
#define EPSV   1e-8f

// ---------------- init: zero V and s in workspace (re-poisoned every call) --
__global__ void caps_init(float* __restrict__ ws) {
  int idx = blockIdx.x * blockDim.x + threadIdx.x;
  if (idx < 2 * NB * NOC * NOD) ws[idx] = 0.0f;
}

// dot of two float4 into acc (function, not macro: a macro param named `w`
// would capture the `.w` member token — that was round 1's compile failure)
__device__ __forceinline__ void dot4(float& acc, const float4& A, const float4& B) {
  acc = fmaf(A.x, B.x, acc);
  acc = fmaf(A.y, B.y, acc);
  acc = fmaf(A.z, B.z, acc);
  acc = fmaf(A.w, B.w, acc);
}

// ---------------- main routing pass ----------------------------------------
// grid = NCHUNK*8 = 1024 blocks, 256 threads (4 waves).
// Convoy swizzle: bid = 64t + 8s + x  ->  chunk = 8t + x (same-XCD, adjacent
// dispatch for the 8 blocks sharing one W chunk), b-quad q = s.
// Wave handles one b, ICHUNK i's. Lane = (d = lane&31, h = lane>>5): each
// lane owns out_dim d and o-half h (32 o's in registers).
__global__ __launch_bounds__(256, 3)
void caps_route(const float* __restrict__ x, const float* __restrict__ W,
                const float* __restrict__ V, float* __restrict__ s) {
  const int bid  = blockIdx.x;
  const int xcd  = bid & 7;
  const int slot = (bid >> 3) & 7;
  const int t    = bid >> 6;             // 0..15
  const int chunk = t * 8 + xcd;         // 0..127, chunk -> XCD chunk%8
  const int q    = slot;                 // b-quad 0..7

  const int wv   = __builtin_amdgcn_readfirstlane((int)(threadIdx.x >> 6));
  const int lane = threadIdx.x & 63;
  const int d    = lane & 31;
  const int h    = lane >> 5;
  const int b    = q * 4 + wv;           // 0..31

  const float LOG2E = 1.4426950408889634f;

  // V[b, 32h+oo, d] held in registers for the whole chunk loop
  float vr[32];
#pragma unroll
  for (int oo = 0; oo < 32; ++oo)
    vr[oo] = V[((size_t)b * NOC + 32 * h + oo) * NOD + d];

  float sacc[32];
#pragma unroll
  for (int oo = 0; oo < 32; ++oo) sacc[oo] = 0.0f;

  for (int ii = 0; ii < ICHUNK; ++ii) {
    const int i = chunk * ICHUNK + ii;

    // x[b,i,0:16] — wave-uniform 64 B
    const float4* xp = reinterpret_cast<const float4*>(x + ((size_t)b * NIN + i) * NK);
    const float4 x0 = xp[0], x1 = xp[1], x2 = xp[2], x3 = xp[3];

    // W[i, 32h+oo, d, 0:16]; lanes d=0..31 are contiguous (64 B apart)
    const float* Wp = W + (((size_t)i * NOC + 32 * h) * NOD + d) * NK;

    float u[32];
#pragma unroll
    for (int oo = 0; oo < 32; ++oo) {
      const float4* wp4 = reinterpret_cast<const float4*>(Wp + (size_t)oo * NOD * NK);
      const float4 w0 = wp4[0], w1 = wp4[1], w2 = wp4[2], w3 = wp4[3];
      float acc = 0.0f;
      dot4(acc, w0, x0); dot4(acc, w1, x1); dot4(acc, w2, x2); dot4(acc, w3, x3);
      u[oo] = acc;
    }

    // softmax over o (64): 32 in-lane + cross-half shuffle. logits = u * V.
    float m = -3.4e38f;
#pragma unroll
    for (int oo = 0; oo < 32; ++oo) m = fmaxf(m, u[oo] * vr[oo]);
    m = fmaxf(m, __shfl_xor(m, 32));

    const float mc = m * LOG2E;
    float Z = 0.0f;
#pragma unroll
    for (int oo = 0; oo < 32; ++oo) {
      const float e = exp2f(fmaf(u[oo] * vr[oo], LOG2E, -mc));
      Z += e;
      u[oo] *= e;                 // u now holds e * u_hat
    }
    Z += __shfl_xor(Z, 32);
    const float rz = 1.0f / Z;

#pragma unroll
    for (int oo = 0; oo < 32; ++oo) sacc[oo] = fmaf(u[oo], rz, sacc[oo]);
  }

  // one atomic per (b,o,d) per wave: 2048/ICHUNK = 128 contributions/address
#pragma unroll
  for (int oo = 0; oo < 32; ++oo)
    unsafeAtomicAdd(&s[((size_t)b * NOC + 32 * h + oo) * NOD + d], sacc[oo]);
}

// ---------------- squash + V update (+ re-zero s for next iteration) -------
__global__ void caps_squash(float* __restrict__ s, float* __restrict__ V,
                            float* __restrict__ out, int last) {
  const int o = threadIdx.x;   // 64
  const int b = blockIdx.x;    // 32
  float sv[32];
  float n2 = 0.0f;
#pragma unroll
  for (int dd = 0; dd < 32; ++dd) {
    const size_t idx = ((size_t)b * NOC + o) * NOD + dd;
    sv[dd] = s[idx];
    n2 = fmaf(sv[dd], sv[dd], n2);
    s[idx] = 0.0f;               // ready for next routing pass
  }
  const float r = n2 / ((1.0f + n2) * sqrtf(n2 + EPSV));
#pragma unroll
  for (int dd = 0; dd < 32; ++dd) {
    const size_t idx = ((size_t)b * NOC + o) * NOD + dd;
    const float v = sv[dd] * r;
    if (last) out[idx] = v;
    else      V[idx] += v;
  }
}

// ---------------- launcher -------------------------------------------------
extern "C" void kernel_launch(void* const* d_in, const int* in_sizes, int n_in,
                              void* d_out, int out_size, void* d_ws, size_t ws_size,
                              hipStream_t stream) {
  const float* x = (const float*)d_in[0];
  const float* W = (const float*)d_in[1];
  float* V   = (float*)d_ws;                 // [32,64,32]
  float* s   = V + NB * NOC * NOD;           // [32,64,32]
  float* out = (float*)d_out;

  caps_init<<<(2 * NB * NOC * NOD + 255) / 256, 256, 0, stream>>>(V);

  for (int r = 0; r < NITERS; ++r) {
    caps_route<<<NCHUNK * 8, 256, 0, stream>>>(x, W, V, s);
    caps_squash<<<NB, NOC, 0, stream>>>(s, V, out, r == NITERS - 1 ? 1 : 0);
  }
}

// Round 6
// 4427.688 us; speedup vs baseline: 2.5471x; 2.5471x over previous
//
#include <hip/hip_runtime.h>
#include <math.h>

// DigitCapsules dynamic routing, MI355X.
// x: [32, 2048, 16] f32   W: [2048, 64, 32, 16] f32   out: [32, 64, 32] f32
// Key algebra: b_r = u_hat * V_r with V_r = sum of previous v's  (b starts 0,
// updated b += u_hat*v). So we never materialize b or u_hat; each routing
// iteration is one streaming pass over W recomputing u_hat on the fly.
//
// R5 post-mortem: WRITE_SIZE 3.84GB + VGPR_Count 84 => backend targeted 6
// waves/EU and spilled the ~96-float per-lane state to scratch (6 GB/pass
// round-trip, VALUBusy 5.7%). Fix: pin waves_per_eu(3,3) (168-VGPR budget),
// #pragma unroll 1 on the ii loop, sched_barrier every 8 oo to cap load
// clustering.

#define NB     32
#define NIN    2048
#define NOC    64
#define NOD    32
#define NK     16
#define NITERS 5
#define ICHUNK 16                 // in_caps per wave
#define NCHUNK (NIN / ICHUNK)     // 128
#define EPSV   1e-8f

// ---------------- init: zero V and s in workspace (re-poisoned every call) --
__global__ void caps_init(float* __restrict__ ws) {
  int idx = blockIdx.x * blockDim.x + threadIdx.x;
  if (idx < 2 * NB * NOC * NOD) ws[idx] = 0.0f;
}

// dot of two float4 into acc (function, not macro: a macro param named `w`
// would capture the `.w` member token — that was round 1's compile failure)
__device__ __forceinline__ void dot4(float& acc, const float4& A, const float4& B) {
  acc = fmaf(A.x, B.x, acc);
  acc = fmaf(A.y, B.y, acc);
  acc = fmaf(A.z, B.z, acc);
  acc = fmaf(A.w, B.w, acc);
}

// ---------------- main routing pass ----------------------------------------
// grid = NCHUNK*8 = 1024 blocks, 256 threads (4 waves).
// Convoy swizzle: bid = 64t + 8s + x  ->  chunk = 8t + x (same-XCD, adjacent
// dispatch for the 8 blocks sharing one W chunk), b-quad q = s.
// Wave handles one b, ICHUNK i's. Lane = (d = lane&31, h = lane>>5): each
// lane owns out_dim d and o-half h (32 o's in registers).
__global__
__attribute__((amdgpu_flat_work_group_size(256, 256), amdgpu_waves_per_eu(3, 3)))
void caps_route(const float* __restrict__ x, const float* __restrict__ W,
                const float* __restrict__ V, float* __restrict__ s) {
  const int bid  = blockIdx.x;
  const int xcd  = bid & 7;
  const int slot = (bid >> 3) & 7;
  const int t    = bid >> 6;             // 0..15
  const int chunk = t * 8 + xcd;         // 0..127, chunk -> XCD chunk%8
  const int q    = slot;                 // b-quad 0..7

  const int wv   = __builtin_amdgcn_readfirstlane((int)(threadIdx.x >> 6));
  const int lane = threadIdx.x & 63;
  const int d    = lane & 31;
  const int h    = lane >> 5;
  const int b    = q * 4 + wv;           // 0..31

  const float LOG2E = 1.4426950408889634f;

  // V[b, 32h+oo, d] held in registers for the whole chunk loop
  float vr[32];
#pragma unroll
  for (int oo = 0; oo < 32; ++oo)
    vr[oo] = V[((size_t)b * NOC + 32 * h + oo) * NOD + d];

  float sacc[32];
#pragma unroll
  for (int oo = 0; oo < 32; ++oo) sacc[oo] = 0.0f;

#pragma unroll 1   // keep ii a runtime loop: a 16x unroll clusters 512 loads
  for (int ii = 0; ii < ICHUNK; ++ii) {
    const int i = chunk * ICHUNK + ii;

    // x[b,i,0:16] — wave-uniform 64 B
    const float4* xp = reinterpret_cast<const float4*>(x + ((size_t)b * NIN + i) * NK);
    const float4 x0 = xp[0], x1 = xp[1], x2 = xp[2], x3 = xp[3];

    // W[i, 32h+oo, d, 0:16]; lanes d=0..31 are contiguous (64 B apart)
    const float* Wp = W + (((size_t)i * NOC + 32 * h) * NOD + d) * NK;

    float u[32];
#pragma unroll
    for (int g = 0; g < 4; ++g) {
#pragma unroll
      for (int j = 0; j < 8; ++j) {
        const int oo = g * 8 + j;
        const float4* wp4 = reinterpret_cast<const float4*>(Wp + (size_t)oo * NOD * NK);
        const float4 w0 = wp4[0], w1 = wp4[1], w2 = wp4[2], w3 = wp4[3];
        float acc = 0.0f;
        dot4(acc, w0, x0); dot4(acc, w1, x1); dot4(acc, w2, x2); dot4(acc, w3, x3);
        u[oo] = acc;
      }
      // cap in-flight W loads at one 8-o group (32 VGPRs) so the register
      // allocator never sees 128 pending load dests on top of ~100 live state
      __builtin_amdgcn_sched_barrier(0);
    }

    // softmax over o (64): 32 in-lane + cross-half shuffle. logits = u * V.
    float m = -3.4e38f;
#pragma unroll
    for (int oo = 0; oo < 32; ++oo) m = fmaxf(m, u[oo] * vr[oo]);
    m = fmaxf(m, __shfl_xor(m, 32));

    const float mc = m * LOG2E;
    float Z = 0.0f;
#pragma unroll
    for (int oo = 0; oo < 32; ++oo) {
      const float e = exp2f(fmaf(u[oo] * vr[oo], LOG2E, -mc));
      Z += e;
      u[oo] *= e;                 // u now holds e * u_hat
    }
    Z += __shfl_xor(Z, 32);
    const float rz = 1.0f / Z;

#pragma unroll
    for (int oo = 0; oo < 32; ++oo) sacc[oo] = fmaf(u[oo], rz, sacc[oo]);
  }

  // one atomic per (b,o,d) per wave: 2048/ICHUNK = 128 contributions/address
#pragma unroll
  for (int oo = 0; oo < 32; ++oo)
    unsafeAtomicAdd(&s[((size_t)b * NOC + 32 * h + oo) * NOD + d], sacc[oo]);
}

// ---------------- squash + V update (+ re-zero s for next iteration) -------
__global__ void caps_squash(float* __restrict__ s, float* __restrict__ V,
                            float* __restrict__ out, int last) {
  const int o = threadIdx.x;   // 64
  const int b = blockIdx.x;    // 32
  float sv[32];
  float n2 = 0.0f;
#pragma unroll
  for (int dd = 0; dd < 32; ++dd) {
    const size_t idx = ((size_t)b * NOC + o) * NOD + dd;
    sv[dd] = s[idx];
    n2 = fmaf(sv[dd], sv[dd], n2);
    s[idx] = 0.0f;               // ready for next routing pass
  }
  const float r = n2 / ((1.0f + n2) * sqrtf(n2 + EPSV));
#pragma unroll
  for (int dd = 0; dd < 32; ++dd) {
    const size_t idx = ((size_t)b * NOC + o) * NOD + dd;
    const float v = sv[dd] * r;
    if (last) out[idx] = v;
    else      V[idx] += v;
  }
}

// ---------------- launcher -------------------------------------------------
extern "C" void kernel_launch(void* const* d_in, const int* in_sizes, int n_in,
                              void* d_out, int out_size, void* d_ws, size_t ws_size,
                              hipStream_t stream) {
  const float* x = (const float*)d_in[0];
  const float* W = (const float*)d_in[1];
  float* V   = (float*)d_ws;                 // [32,64,32]
  float* s   = V + NB * NOC * NOD;           // [32,64,32]
  float* out = (float*)d_out;

  caps_init<<<(2 * NB * NOC * NOD + 255) / 256, 256, 0, stream>>>(V);

  for (int r = 0; r < NITERS; ++r) {
    caps_route<<<NCHUNK * 8, 256, 0, stream>>>(x, W, V, s);
    caps_squash<<<NB, NOC, 0, stream>>>(s, V, out, r == NITERS - 1 ? 1 : 0);
  }
}